// Round 1
// baseline (136.673 us; speedup 1.0000x reference)
//
#include <hip/hip_runtime.h>

typedef __attribute__((ext_vector_type(8))) short bf16x8;
typedef __attribute__((ext_vector_type(4))) float f32x4;

__device__ __forceinline__ unsigned short f2bf(float f) {
    unsigned u = __float_as_uint(f);
    unsigned r = (u + 0x7FFFu + ((u >> 16) & 1u)) >> 16;   // RNE
    return (unsigned short)r;
}

__device__ __forceinline__ void gload16(const unsigned short* g, unsigned short* l) {
    __builtin_amdgcn_global_load_lds((const __attribute__((address_space(1))) void*)g,
                                     (__attribute__((address_space(3))) void*)l, 16, 0, 0);
}

// ---------------- conversion kernels ----------------

__global__ void conv_x_kernel(const float* __restrict__ x, unsigned short* __restrict__ xb, int total8) {
    int i = blockIdx.x * blockDim.x + threadIdx.x;
    if (i >= total8) return;
    const float4* xv = (const float4*)x;
    float4 a = xv[(size_t)i * 2];
    float4 b = xv[(size_t)i * 2 + 1];
    uint4 o;
    o.x = (unsigned)f2bf(a.x) | ((unsigned)f2bf(a.y) << 16);
    o.y = (unsigned)f2bf(a.z) | ((unsigned)f2bf(a.w) << 16);
    o.z = (unsigned)f2bf(b.x) | ((unsigned)f2bf(b.y) << 16);
    o.w = (unsigned)f2bf(b.z) | ((unsigned)f2bf(b.w) << 16);
    ((uint4*)xb)[i] = o;
}

// one block per center row: bf16 convert + exact fp32 ||c||^2  (assumes D == 1024)
__global__ void conv_c_kernel(const float* __restrict__ c, unsigned short* __restrict__ cb,
                              float* __restrict__ c2, int D) {
    int k = blockIdx.x;
    int tid = threadIdx.x;                      // 256 threads, 4 elems each
    const float4 v = ((const float4*)(c + (long)k * D))[tid];
    uint2 o;
    o.x = (unsigned)f2bf(v.x) | ((unsigned)f2bf(v.y) << 16);
    o.y = (unsigned)f2bf(v.z) | ((unsigned)f2bf(v.w) << 16);
    ((uint2*)(cb + (long)k * D))[tid] = o;
    float s = v.x * v.x + v.y * v.y + v.z * v.z + v.w * v.w;
    #pragma unroll
    for (int d = 1; d < 64; d <<= 1) s += __shfl_xor(s, d, 64);
    __shared__ float wsum[4];
    int lane = tid & 63, w = tid >> 6;
    if (lane == 0) wsum[w] = s;
    __syncthreads();
    if (tid == 0) c2[k] = wsum[0] + wsum[1] + wsum[2] + wsum[3];
}

__global__ void init_packed_kernel(unsigned long long* __restrict__ p, int n) {
    int i = blockIdx.x * blockDim.x + threadIdx.x;
    if (i < n) p[i] = ~0ull;
}

// ---------------- GEMM + argmin ----------------
// 128x128 tile, BK=32, 4 waves (each 64x64), mfma_f32_16x16x32_bf16.
// LDS linear (global_load_lds), bank conflicts broken by pre-swizzling the
// GLOBAL source k-slot (m173 pattern) + matching XOR on the ds_read k-slot.
__global__ void gemm_argmin_kernel(const unsigned short* __restrict__ Xb,
                                   const unsigned short* __restrict__ Cb,
                                   const float* __restrict__ c2,
                                   unsigned long long* __restrict__ packed,
                                   int D) {
    __shared__ unsigned short As[128 * 32];
    __shared__ unsigned short Bs[128 * 32];
    const int tid  = threadIdx.x;
    const int lane = tid & 63;
    const int w    = tid >> 6;
    const int wr   = w >> 1, wc = w & 1;
    const long rowbase = (long)blockIdx.x * 128;
    const int  colbase = blockIdx.y * 128;

    // staging: thread covers (row = tid>>2, 16B slot = tid&3).  Slot s at row r
    // holds logical k-block q = s ^ f(r), f(r) = (r&3) ^ ((r>>2)&3).
    const int srow = tid >> 2;
    const int sq   = (tid & 3) ^ ((tid >> 2) & 3) ^ ((tid >> 4) & 3);
    const int scol = sq * 8;
    const unsigned short* ga0 = Xb + (rowbase + srow) * D + scol;
    const unsigned short* ga1 = Xb + (rowbase + 64 + srow) * D + scol;
    const unsigned short* gb0 = Cb + ((long)colbase + srow) * D + scol;
    const unsigned short* gb1 = Cb + ((long)colbase + 64 + srow) * D + scol;
    unsigned short* lA0 = &As[w * 512];
    unsigned short* lA1 = &As[2048 + w * 512];
    unsigned short* lB0 = &Bs[w * 512];
    unsigned short* lB1 = &Bs[2048 + w * 512];

    // fragment reads: row-in-frag fr = lane&15, logical k-group q = lane>>4,
    // physical slot = q ^ f(row) with f(row) = (lane&3) ^ ((lane&12)>>2)
    const int fr    = lane & 15;
    const int fq    = (lane >> 4) ^ (lane & 3) ^ ((lane & 12) >> 2);
    const int koffe = fq * 8;

    f32x4 acc[4][4] = {};

    for (int k0 = 0; k0 < D; k0 += 32) {
        gload16(ga0 + k0, lA0);
        gload16(ga1 + k0, lA1);
        gload16(gb0 + k0, lB0);
        gload16(gb1 + k0, lB1);
        __syncthreads();
        bf16x8 af[4], bfr[4];
        #pragma unroll
        for (int m = 0; m < 4; ++m)
            af[m] = *(const bf16x8*)&As[(wr * 64 + m * 16 + fr) * 32 + koffe];
        #pragma unroll
        for (int n = 0; n < 4; ++n)
            bfr[n] = *(const bf16x8*)&Bs[(wc * 64 + n * 16 + fr) * 32 + koffe];
        #pragma unroll
        for (int m = 0; m < 4; ++m)
            #pragma unroll
            for (int n = 0; n < 4; ++n)
                acc[m][n] = __builtin_amdgcn_mfma_f32_16x16x32_bf16(af[m], bfr[n], acc[m][n], 0, 0, 0);
        __syncthreads();
    }

    // argmin epilogue: score = c2[k] - 2*dot.  C/D layout: col=lane&15, row=(lane>>4)*4+reg.
    float c2v[4];
    int   kcol[4];
    #pragma unroll
    for (int n = 0; n < 4; ++n) {
        kcol[n] = colbase + wc * 64 + n * 16 + fr;
        c2v[n]  = c2[kcol[n]];
    }
    #pragma unroll
    for (int m = 0; m < 4; ++m) {
        #pragma unroll
        for (int reg = 0; reg < 4; ++reg) {
            unsigned long long best = ~0ull;
            #pragma unroll
            for (int n = 0; n < 4; ++n) {
                float score = c2v[n] - 2.0f * acc[m][n][reg];
                unsigned u = __float_as_uint(score);
                u ^= (u >> 31) ? 0xFFFFFFFFu : 0x80000000u;   // order-preserving map
                unsigned long long cand = ((unsigned long long)u << 32) | (unsigned)kcol[n];
                best = cand < best ? cand : best;
            }
            #pragma unroll
            for (int s = 1; s < 16; s <<= 1) {
                unsigned long long other = __shfl_xor(best, s, 64);
                best = other < best ? other : best;
            }
            if ((lane & 15) == 0) {
                long row = rowbase + wr * 64 + m * 16 + ((lane >> 4) << 2) + reg;
                atomicMin(&packed[row], best);   // min is order-independent -> deterministic
            }
        }
    }
}

__global__ void extract_labels_kernel(const unsigned long long* __restrict__ p,
                                      unsigned* __restrict__ lab, int n) {
    int i = blockIdx.x * blockDim.x + threadIdx.x;
    if (i < n) lab[i] = (unsigned)(p[i] & 0xFFFFFFFFull);
}

// ---------------- segmented sum + finalize ----------------
// one block per cluster; deterministic ballot+prefix compaction; thread owns 4 columns.
__global__ void segsum_kernel(const unsigned* __restrict__ labels,
                              const float* __restrict__ emb,
                              const float* __restrict__ centers,
                              const int* __restrict__ cnt,
                              float* __restrict__ out,
                              int N, int D) {
    const int k = blockIdx.x;
    const int tid = threadIdx.x;
    const int lane = tid & 63, w = tid >> 6;
    __shared__ int idxbuf[1024];
    __shared__ int cnts[16];            // [s][w]
    float4 acc = {0.f, 0.f, 0.f, 0.f};
    int mtot = 0;
    for (int base = 0; base < N; base += 1024) {
        bool mt[4];
        unsigned long long bal[4];
        #pragma unroll
        for (int s = 0; s < 4; ++s) {
            int n = base + s * 256 + tid;
            mt[s]  = (labels[n] == (unsigned)k);
            bal[s] = __ballot(mt[s]);
            if (lane == 0) cnts[s * 4 + w] = (int)__popcll(bal[s]);
        }
        __syncthreads();
        int myoff[4];
        int run = 0;
        #pragma unroll
        for (int s = 0; s < 4; ++s) {
            #pragma unroll
            for (int w2 = 0; w2 < 4; ++w2) {
                if (w2 == w) myoff[s] = run;
                run += cnts[s * 4 + w2];
            }
        }
        const int total = run;
        #pragma unroll
        for (int s = 0; s < 4; ++s) {
            if (mt[s]) {
                int pos = myoff[s] + (int)__popcll(bal[s] & ((1ull << lane) - 1ull));
                idxbuf[pos] = base + s * 256 + tid;
            }
        }
        __syncthreads();
        for (int j = 0; j < total; ++j) {
            const float4 v = *(const float4*)(emb + (long)idxbuf[j] * D + tid * 4);
            acc.x += v.x; acc.y += v.y; acc.z += v.z; acc.w += v.w;
        }
        mtot += total;
        __syncthreads();
    }
    const float4 cv = *(const float4*)(centers + (long)k * D + tid * 4);
    float4 o;
    if (mtot > 0) {
        float ccn = 0.5f * (float)cnt[k] + 0.5f * (float)mtot;
        float lr  = 1.0f / (ccn + 1.0f);
        float im  = 1.0f / (float)mtot;
        float om  = 1.0f - lr;
        o.x = om * cv.x + lr * (acc.x * im);
        o.y = om * cv.y + lr * (acc.y * im);
        o.z = om * cv.z + lr * (acc.z * im);
        o.w = om * cv.w + lr * (acc.w * im);
    } else {
        o = cv;
    }
    *(float4*)(out + (long)k * D + tid * 4) = o;
}

// ---------------- launch ----------------

extern "C" void kernel_launch(void* const* d_in, const int* in_sizes, int n_in,
                              void* d_out, int out_size, void* d_ws, size_t ws_size,
                              hipStream_t stream) {
    const float* emb = (const float*)d_in[0];
    const float* cen = (const float*)d_in[1];
    const int*   cnt = (const int*)d_in[2];
    float* out = (float*)d_out;
    const int K = in_sizes[2];
    const int D = in_sizes[1] / K;      // 1024
    const int N = in_sizes[0] / D;      // 16384

    char* ws = (char*)d_ws;
    size_t xb_bytes = (size_t)N * D * 2;
    size_t cb_bytes = (size_t)K * D * 2;
    unsigned short* Xb = (unsigned short*)ws;
    unsigned short* Cb = (unsigned short*)(ws + xb_bytes);
    float* c2 = (float*)(ws + xb_bytes + cb_bytes);
    unsigned long long* packed = (unsigned long long*)(ws + xb_bytes + cb_bytes + (size_t)K * 4);
    unsigned* labels = (unsigned*)(ws + xb_bytes + cb_bytes + (size_t)K * 4 + (size_t)N * 8);

    int total8 = N * D / 8;
    conv_x_kernel<<<dim3((total8 + 255) / 256), dim3(256), 0, stream>>>(emb, Xb, total8);
    conv_c_kernel<<<dim3(K), dim3(256), 0, stream>>>(cen, Cb, c2, D);
    init_packed_kernel<<<dim3((N + 255) / 256), dim3(256), 0, stream>>>(packed, N);
    gemm_argmin_kernel<<<dim3(N / 128, K / 128), dim3(256), 0, stream>>>(Xb, Cb, c2, packed, D);
    extract_labels_kernel<<<dim3((N + 255) / 256), dim3(256), 0, stream>>>(packed, labels, N);
    segsum_kernel<<<dim3(K), dim3(256), 0, stream>>>(labels, emb, cen, cnt, out, N, D);
}

// Round 2
// 106.626 us; speedup vs baseline: 1.2818x; 1.2818x over previous
//
#include <hip/hip_runtime.h>

typedef __attribute__((ext_vector_type(8))) short bf16x8;
typedef __attribute__((ext_vector_type(4))) float f32x4;

__device__ __forceinline__ unsigned short f2bf(float f) {
    unsigned u = __float_as_uint(f);
    unsigned r = (u + 0x7FFFu + ((u >> 16) & 1u)) >> 16;   // RNE
    return (unsigned short)r;
}

__device__ __forceinline__ void gload16(const unsigned short* g, unsigned short* l) {
    __builtin_amdgcn_global_load_lds((const __attribute__((address_space(1))) void*)g,
                                     (__attribute__((address_space(3))) void*)l, 16, 0, 0);
}

// ---------------- conversion kernels ----------------

__global__ void conv_x_kernel(const float* __restrict__ x, unsigned short* __restrict__ xb, int total8) {
    int i = blockIdx.x * blockDim.x + threadIdx.x;
    if (i >= total8) return;
    const float4* xv = (const float4*)x;
    float4 a = xv[(size_t)i * 2];
    float4 b = xv[(size_t)i * 2 + 1];
    uint4 o;
    o.x = (unsigned)f2bf(a.x) | ((unsigned)f2bf(a.y) << 16);
    o.y = (unsigned)f2bf(a.z) | ((unsigned)f2bf(a.w) << 16);
    o.z = (unsigned)f2bf(b.x) | ((unsigned)f2bf(b.y) << 16);
    o.w = (unsigned)f2bf(b.z) | ((unsigned)f2bf(b.w) << 16);
    ((uint4*)xb)[i] = o;
}

// one block per center row: bf16 convert + exact fp32 ||c||^2  (assumes D == 1024)
__global__ void conv_c_kernel(const float* __restrict__ c, unsigned short* __restrict__ cb,
                              float* __restrict__ c2, int D) {
    int k = blockIdx.x;
    int tid = threadIdx.x;                      // 256 threads, 4 elems each
    const float4 v = ((const float4*)(c + (long)k * D))[tid];
    uint2 o;
    o.x = (unsigned)f2bf(v.x) | ((unsigned)f2bf(v.y) << 16);
    o.y = (unsigned)f2bf(v.z) | ((unsigned)f2bf(v.w) << 16);
    ((uint2*)(cb + (long)k * D))[tid] = o;
    float s = v.x * v.x + v.y * v.y + v.z * v.z + v.w * v.w;
    #pragma unroll
    for (int d = 1; d < 64; d <<= 1) s += __shfl_xor(s, d, 64);
    __shared__ float wsum[4];
    int lane = tid & 63, w = tid >> 6;
    if (lane == 0) wsum[w] = s;
    __syncthreads();
    if (tid == 0) c2[k] = wsum[0] + wsum[1] + wsum[2] + wsum[3];
}

__global__ void init_packed_kernel(unsigned long long* __restrict__ p, int n) {
    int i = blockIdx.x * blockDim.x + threadIdx.x;
    if (i < n) p[i] = ~0ull;
}

// ---------------- GEMM + argmin ----------------
// 128x128 tile, BK=32, 4 waves (each 64x64), mfma_f32_16x16x32_bf16.
// LDS linear (global_load_lds), bank conflicts broken by pre-swizzling the
// GLOBAL source k-slot (m173 pattern) + matching XOR on the ds_read k-slot.
__global__ void gemm_argmin_kernel(const unsigned short* __restrict__ Xb,
                                   const unsigned short* __restrict__ Cb,
                                   const float* __restrict__ c2,
                                   unsigned long long* __restrict__ packed,
                                   int D) {
    __shared__ unsigned short As[128 * 32];
    __shared__ unsigned short Bs[128 * 32];
    const int tid  = threadIdx.x;
    const int lane = tid & 63;
    const int w    = tid >> 6;
    const int wr   = w >> 1, wc = w & 1;
    const long rowbase = (long)blockIdx.x * 128;
    const int  colbase = blockIdx.y * 128;

    const int srow = tid >> 2;
    const int sq   = (tid & 3) ^ ((tid >> 2) & 3) ^ ((tid >> 4) & 3);
    const int scol = sq * 8;
    const unsigned short* ga0 = Xb + (rowbase + srow) * D + scol;
    const unsigned short* ga1 = Xb + (rowbase + 64 + srow) * D + scol;
    const unsigned short* gb0 = Cb + ((long)colbase + srow) * D + scol;
    const unsigned short* gb1 = Cb + ((long)colbase + 64 + srow) * D + scol;
    unsigned short* lA0 = &As[w * 512];
    unsigned short* lA1 = &As[2048 + w * 512];
    unsigned short* lB0 = &Bs[w * 512];
    unsigned short* lB1 = &Bs[2048 + w * 512];

    const int fr    = lane & 15;
    const int fq    = (lane >> 4) ^ (lane & 3) ^ ((lane & 12) >> 2);
    const int koffe = fq * 8;

    f32x4 acc[4][4] = {};

    for (int k0 = 0; k0 < D; k0 += 32) {
        gload16(ga0 + k0, lA0);
        gload16(ga1 + k0, lA1);
        gload16(gb0 + k0, lB0);
        gload16(gb1 + k0, lB1);
        __syncthreads();
        bf16x8 af[4], bfr[4];
        #pragma unroll
        for (int m = 0; m < 4; ++m)
            af[m] = *(const bf16x8*)&As[(wr * 64 + m * 16 + fr) * 32 + koffe];
        #pragma unroll
        for (int n = 0; n < 4; ++n)
            bfr[n] = *(const bf16x8*)&Bs[(wc * 64 + n * 16 + fr) * 32 + koffe];
        #pragma unroll
        for (int m = 0; m < 4; ++m)
            #pragma unroll
            for (int n = 0; n < 4; ++n)
                acc[m][n] = __builtin_amdgcn_mfma_f32_16x16x32_bf16(af[m], bfr[n], acc[m][n], 0, 0, 0);
        __syncthreads();
    }

    // argmin epilogue: score = c2[k] - 2*dot.  C/D layout: col=lane&15, row=(lane>>4)*4+reg.
    float c2v[4];
    int   kcol[4];
    #pragma unroll
    for (int n = 0; n < 4; ++n) {
        kcol[n] = colbase + wc * 64 + n * 16 + fr;
        c2v[n]  = c2[kcol[n]];
    }
    #pragma unroll
    for (int m = 0; m < 4; ++m) {
        #pragma unroll
        for (int reg = 0; reg < 4; ++reg) {
            unsigned long long best = ~0ull;
            #pragma unroll
            for (int n = 0; n < 4; ++n) {
                float score = c2v[n] - 2.0f * acc[m][n][reg];
                unsigned u = __float_as_uint(score);
                u ^= (u >> 31) ? 0xFFFFFFFFu : 0x80000000u;   // order-preserving map
                unsigned long long cand = ((unsigned long long)u << 32) | (unsigned)kcol[n];
                best = cand < best ? cand : best;
            }
            #pragma unroll
            for (int s = 1; s < 16; s <<= 1) {
                unsigned long long other = __shfl_xor(best, s, 64);
                best = other < best ? other : best;
            }
            if ((lane & 15) == 0) {
                long row = rowbase + wr * 64 + m * 16 + ((lane >> 4) << 2) + reg;
                atomicMin(&packed[row], best);   // min is order-independent -> deterministic
            }
        }
    }
}

__global__ void extract_labels_kernel(const unsigned long long* __restrict__ p,
                                      unsigned* __restrict__ lab, int n) {
    int i = blockIdx.x * blockDim.x + threadIdx.x;
    if (i < n) lab[i] = (unsigned)(p[i] & 0xFFFFFFFFull);
}

// ---------------- segmented sum: sliced partials ----------------
// grid (K clusters, S=4 N-slices); 1024 threads = 4 row-groups x 256 col-threads.
// Block (k,s): ballot-compacts matching indices in its N-slice (deterministic),
// row-groups gather every 4th matching row in parallel, LDS-reduce, write
// fp32 partial [k][s][D] + count.  All orders fixed -> bitwise deterministic.
__global__ void segsum_partial_kernel(const unsigned* __restrict__ labels,
                                      const float* __restrict__ emb,
                                      float* __restrict__ partial,
                                      int* __restrict__ pcount,
                                      int N, int D) {
    const int k   = blockIdx.x;
    const int s   = blockIdx.y;
    const int tid = threadIdx.x;          // 0..1023
    const int grp = tid >> 8;             // row-group 0..3
    const int ct  = tid & 255;            // col-thread: owns cols ct*4..ct*4+3
    const int lane = tid & 63, w = tid >> 6;

    __shared__ int idxbuf[4096];
    __shared__ int cnts[16];
    __shared__ float4 red[4][256];

    const int slice = N >> 2;             // 4096
    const int base0 = s * slice;
    int total = 0;
    for (int base = base0; base < base0 + slice; base += 1024) {
        const int n = base + tid;
        const bool m = (labels[n] == (unsigned)k);
        const unsigned long long bal = __ballot(m);
        if (lane == 0) cnts[w] = (int)__popcll(bal);
        __syncthreads();
        int myoff = total, run = total;
        #pragma unroll
        for (int w2 = 0; w2 < 16; ++w2) {
            if (w2 == w) myoff = run;
            run += cnts[w2];
        }
        if (m) idxbuf[myoff + (int)__popcll(bal & ((1ull << lane) - 1ull))] = n;
        total = run;
        __syncthreads();
    }

    float4 acc = {0.f, 0.f, 0.f, 0.f};
    for (int j = grp; j < total; j += 4) {
        const int row = idxbuf[j];        // LDS broadcast (uniform within group)
        const float4 v = *(const float4*)(emb + (long)row * D + ct * 4);
        acc.x += v.x; acc.y += v.y; acc.z += v.z; acc.w += v.w;
    }
    red[grp][ct] = acc;
    __syncthreads();
    if (grp == 0) {
        float4 r = red[0][ct];
        #pragma unroll
        for (int g = 1; g < 4; ++g) {
            const float4 q = red[g][ct];
            r.x += q.x; r.y += q.y; r.z += q.z; r.w += q.w;
        }
        *(float4*)(partial + ((long)(k * 4 + s)) * D + ct * 4) = r;
    }
    if (tid == 0) pcount[k * 4 + s] = total;
}

// one block per cluster: reduce 4 slice partials (fixed order) + EMA finalize
__global__ void finalize_kernel(const float* __restrict__ partial,
                                const int* __restrict__ pcount,
                                const float* __restrict__ centers,
                                const int* __restrict__ cnt,
                                float* __restrict__ out, int D) {
    const int k = blockIdx.x;
    const int ct = threadIdx.x;           // 256 threads, 4 cols each
    float4 acc = {0.f, 0.f, 0.f, 0.f};
    int mtot = 0;
    #pragma unroll
    for (int s = 0; s < 4; ++s) {
        const float4 p = *(const float4*)(partial + ((long)(k * 4 + s)) * D + ct * 4);
        acc.x += p.x; acc.y += p.y; acc.z += p.z; acc.w += p.w;
        mtot += pcount[k * 4 + s];
    }
    const float4 cv = *(const float4*)(centers + (long)k * D + ct * 4);
    float4 o;
    if (mtot > 0) {
        float ccn = 0.5f * (float)cnt[k] + 0.5f * (float)mtot;
        float lr  = 1.0f / (ccn + 1.0f);
        float im  = 1.0f / (float)mtot;
        float om  = 1.0f - lr;
        o.x = om * cv.x + lr * (acc.x * im);
        o.y = om * cv.y + lr * (acc.y * im);
        o.z = om * cv.z + lr * (acc.z * im);
        o.w = om * cv.w + lr * (acc.w * im);
    } else {
        o = cv;
    }
    *(float4*)(out + (long)k * D + ct * 4) = o;
}

// ---------------- launch ----------------

extern "C" void kernel_launch(void* const* d_in, const int* in_sizes, int n_in,
                              void* d_out, int out_size, void* d_ws, size_t ws_size,
                              hipStream_t stream) {
    const float* emb = (const float*)d_in[0];
    const float* cen = (const float*)d_in[1];
    const int*   cnt = (const int*)d_in[2];
    float* out = (float*)d_out;
    const int K = in_sizes[2];
    const int D = in_sizes[1] / K;      // 1024
    const int N = in_sizes[0] / D;      // 16384

    char* ws = (char*)d_ws;
    size_t xb_bytes = (size_t)N * D * 2;            // 32 MB
    size_t cb_bytes = (size_t)K * D * 2;            // 2 MB
    unsigned short* Xb = (unsigned short*)ws;
    unsigned short* Cb = (unsigned short*)(ws + xb_bytes);
    float* c2 = (float*)(ws + xb_bytes + cb_bytes);
    unsigned long long* packed = (unsigned long long*)(ws + xb_bytes + cb_bytes + (size_t)K * 4);
    unsigned* labels = (unsigned*)(ws + xb_bytes + cb_bytes + (size_t)K * 4 + (size_t)N * 8);
    // partial sums alias the Xb region (Xb/Cb are dead after gemm_argmin_kernel;
    // same-stream ordering makes the reuse safe).  16 MB + 16 KB.
    float* partial = (float*)ws;
    int* pcount = (int*)(ws + (size_t)K * 4 * D * 4);

    int total8 = N * D / 8;
    conv_x_kernel<<<dim3((total8 + 255) / 256), dim3(256), 0, stream>>>(emb, Xb, total8);
    conv_c_kernel<<<dim3(K), dim3(256), 0, stream>>>(cen, Cb, c2, D);
    init_packed_kernel<<<dim3((N + 255) / 256), dim3(256), 0, stream>>>(packed, N);
    gemm_argmin_kernel<<<dim3(N / 128, K / 128), dim3(256), 0, stream>>>(Xb, Cb, c2, packed, D);
    extract_labels_kernel<<<dim3((N + 255) / 256), dim3(256), 0, stream>>>(packed, labels, N);
    segsum_partial_kernel<<<dim3(K, 4), dim3(1024), 0, stream>>>(labels, emb, partial, pcount, N, D);
    finalize_kernel<<<dim3(K), dim3(256), 0, stream>>>(partial, pcount, cen, cnt, out, D);
}